// Round 1
// baseline (47.232 us; speedup 1.0000x reference)
//
#include <hip/hip_runtime.h>

// ---------------------------------------------------------------------------
// QuantumLayer: reference collapses to
//   T = product of 78 effective 2x2 gates applied to (1,0)   (same for all rows)
//   out[b,j] = |T_j? + noise[b,j]| / norm_b
// where noise = jax.random.normal(key(42),(256,8192),c64)*0.01 (threefry2x32,
// partitionable mode) and only j==0,1 carry signal (T00, T10).
// ---------------------------------------------------------------------------

#define NBATCH 256
#define NDIM   8192u

__host__ __device__ __forceinline__ unsigned rotl32(unsigned v, unsigned d) {
  return (v << d) | (v >> (32u - d));
}

// Threefry-2x32, 20 rounds, exactly as jax._src.prng.threefry2x32.
__host__ __device__ inline void tf2x32(unsigned k0, unsigned k1,
                                       unsigned x0, unsigned x1,
                                       unsigned& o0, unsigned& o1) {
  const unsigned k2 = k0 ^ k1 ^ 0x1BD11BDAu;
  x0 += k0; x1 += k1;
#define TF_R(r) { x0 += x1; x1 = rotl32(x1, r); x1 ^= x0; }
  TF_R(13u) TF_R(15u) TF_R(26u) TF_R(6u)
  x0 += k1; x1 += k2 + 1u;
  TF_R(17u) TF_R(29u) TF_R(16u) TF_R(24u)
  x0 += k2; x1 += k0 + 2u;
  TF_R(13u) TF_R(15u) TF_R(26u) TF_R(6u)
  x0 += k0; x1 += k1 + 3u;
  TF_R(17u) TF_R(29u) TF_R(16u) TF_R(24u)
  x0 += k1; x1 += k2 + 4u;
  TF_R(13u) TF_R(15u) TF_R(26u) TF_R(6u)
  x0 += k2; x1 += k0 + 5u;
#undef TF_R
  o0 = x0; o1 = x1;
}

// JAX _uniform(lo=nextafter(-1,0), hi=1) for float32 from 32 random bits.
__device__ __forceinline__ float bits_to_u(unsigned bits) {
  float f = __uint_as_float((bits >> 9) | 0x3f800000u) - 1.0f; // [0, 1-2^-23]
  const float LO = -0.99999994f; // nextafter(-1,0); (hi-lo) rounds to 2.0f
  return fmaxf(LO, fmaf(f, 2.0f, LO));
}

// Giles erfinvf — same coefficients XLA's ErfInv32 uses (log1p based).
__device__ __forceinline__ float erfinv_f(float x) {
  float w = -log1pf(-x * x);
  float p;
  if (w < 5.0f) {
    w -= 2.5f;
    p = 2.81022636e-08f;
    p = fmaf(p, w, 3.43273939e-07f);
    p = fmaf(p, w, -3.5233877e-06f);
    p = fmaf(p, w, -4.39150654e-06f);
    p = fmaf(p, w, 0.00021858087f);
    p = fmaf(p, w, -0.00125372503f);
    p = fmaf(p, w, -0.00417768164f);
    p = fmaf(p, w, 0.246640727f);
    p = fmaf(p, w, 1.50140941f);
  } else {
    w = sqrtf(w) - 3.0f;
    p = -0.000200214257f;
    p = fmaf(p, w, 0.000100950558f);
    p = fmaf(p, w, 0.00134934322f);
    p = fmaf(p, w, -0.00367342844f);
    p = fmaf(p, w, 0.00573950773f);
    p = fmaf(p, w, -0.0076224613f);
    p = fmaf(p, w, 0.00943887047f);
    p = fmaf(p, w, 1.00167406f);
    p = fmaf(p, w, 2.83297682f);
  }
  return p * x;
}

// 78-step 2x2 effective-gate chain applied to (1,0). One thread; f32 trig
// (matches reference precision) with f64 accumulation for safety.
__global__ void gate_kernel(const float* __restrict__ rx,
                            const float* __restrict__ ry,
                            const float* __restrict__ rz,
                            float* __restrict__ T) {
  if (threadIdx.x != 0 || blockIdx.x != 0) return;
  double er = 1.0, ei = 0.0, pr = 0.0, pi = 0.0; // e (even), o (odd) amplitudes
  // RX: m = [[c, -is],[-is, c]];  e' = c e + (-is) o ; o' = (-is) e' + c o
  for (int i = 0; i < 26; ++i) {
    float a = rx[i] * 0.5f;
    double c = (double)cosf(a), s = (double)sinf(a);
    double er2 = c * er + s * pi;
    double ei2 = c * ei - s * pr;
    double pr2 = s * ei2 + c * pr;
    double pi2 = -s * er2 + c * pi;
    er = er2; ei = ei2; pr = pr2; pi = pi2;
  }
  // RY: m = [[c,-s],[s,c]];  e' = c e - s o ; o' = s e' + c o
  for (int i = 0; i < 26; ++i) {
    float a = ry[i] * 0.5f;
    double c = (double)cosf(a), s = (double)sinf(a);
    double er2 = c * er - s * pr;
    double ei2 = c * ei - s * pi;
    double pr2 = s * er2 + c * pr;
    double pi2 = s * ei2 + c * pi;
    er = er2; ei = ei2; pr = pr2; pi = pi2;
  }
  // RZ: e' = (c - is) e ; o' = (c + is) o   (m10 = 0, bug is a no-op here)
  for (int i = 0; i < 26; ++i) {
    float a = rz[i] * 0.5f;
    double c = (double)cosf(a), s = (double)sinf(a);
    double er2 = c * er + s * ei;
    double ei2 = c * ei - s * er;
    double pr2 = c * pr - s * pi;
    double pi2 = c * pi + s * pr;
    er = er2; ei = ei2; pr = pr2; pi = pi2;
  }
  T[0] = (float)er; T[1] = (float)ei; T[2] = (float)pr; T[3] = (float)pi;
}

// One block per batch row; 1024 threads x 8 columns each.
__global__ __launch_bounds__(1024) void noise_kernel(
    const float* __restrict__ T, float* __restrict__ out,
    unsigned kr0, unsigned kr1, unsigned ki0, unsigned ki1) {
  const int b = blockIdx.x;
  const int t = threadIdx.x;
  const unsigned base = (unsigned)b * NDIM;

  float re[8], im[8];
#pragma unroll
  for (int k = 0; k < 8; ++k) {
    unsigned j = base + (unsigned)t * 8u + (unsigned)k; // flat index into (256,8192)
    unsigned y0, y1;
    // partitionable random_bits: counts = (hi32(j)=0, lo32(j)=j), bits = w0^w1
    tf2x32(kr0, kr1, 0u, j, y0, y1);
    re[k] = erfinv_f(bits_to_u(y0 ^ y1)) * 0.01f;
    tf2x32(ki0, ki1, 0u, j, y0, y1);
    im[k] = erfinv_f(bits_to_u(y0 ^ y1)) * 0.01f;
  }
  if (t == 0) { // columns 0 and 1 carry the circuit amplitudes
    re[0] += T[0]; im[0] += T[1];
    re[1] += T[2]; im[1] += T[3];
  }

  float sumsq = 0.0f;
  float a[8];
#pragma unroll
  for (int k = 0; k < 8; ++k) {
    float s2 = fmaf(re[k], re[k], im[k] * im[k]);
    sumsq += s2;
    a[k] = sqrtf(s2);
  }

  // block-wide reduction: wave64 shuffle, then 16 wave partials via LDS
#pragma unroll
  for (int off = 32; off; off >>= 1) sumsq += __shfl_down(sumsq, off);
  __shared__ float wsum[16];
  __shared__ float s_rnorm;
  if ((t & 63) == 0) wsum[t >> 6] = sumsq;
  __syncthreads();
  if (t < 64) {
    float v = (t < 16) ? wsum[t] : 0.0f;
#pragma unroll
    for (int off = 8; off; off >>= 1) v += __shfl_xor(v, off);
    if (t == 0) s_rnorm = rsqrtf(v);
  }
  __syncthreads();
  const float rn = s_rnorm;

  float4 o0 = make_float4(a[0] * rn, a[1] * rn, a[2] * rn, a[3] * rn);
  float4 o1 = make_float4(a[4] * rn, a[5] * rn, a[6] * rn, a[7] * rn);
  float4* op = (float4*)(out + base + (unsigned)t * 8u);
  op[0] = o0;
  op[1] = o1;
}

extern "C" void kernel_launch(void* const* d_in, const int* in_sizes, int n_in,
                              void* d_out, int out_size, void* d_ws, size_t ws_size,
                              hipStream_t stream) {
  (void)in_sizes; (void)n_in; (void)out_size; (void)ws_size;
  // inputs: 0=x (unused), 1=rx_params(26), 2=ry_params(26), 3=rz_params(26)
  const float* rx = (const float*)d_in[1];
  const float* ry = (const float*)d_in[2];
  const float* rz = (const float*)d_in[3];
  float* T = (float*)d_ws;   // 4 floats: T00.re, T00.im, T10.re, T10.im
  float* out = (float*)d_out;

  // jax.random.key(42) -> (0,42); partitionable fold-like split for complex
  // normal: key_re = TF(key,(0,0)) both words, key_im = TF(key,(0,1)).
  unsigned kr0, kr1, ki0, ki1;
  tf2x32(0u, 42u, 0u, 0u, kr0, kr1);
  tf2x32(0u, 42u, 0u, 1u, ki0, ki1);

  gate_kernel<<<1, 64, 0, stream>>>(rx, ry, rz, T);
  noise_kernel<<<NBATCH, 1024, 0, stream>>>(T, out, kr0, kr1, ki0, ki1);
}

// Round 2
// 19.729 us; speedup vs baseline: 2.3941x; 2.3941x over previous
//
#include <hip/hip_runtime.h>

// ---------------------------------------------------------------------------
// QuantumLayer: reference collapses to
//   T = ordered product of 78 effective 2x2 gates applied to (1,0)  (batch-invariant)
//   out[b,j] = |T_j? + noise[b,j]| / norm_b
// noise = jax.random.normal(key(42),(256,8192),c64)*0.01, threefry2x32
// partitionable mode (verified bit-match in round 1, absmax 1.2e-4).
// This round: single fused kernel. Wave 0 of each block computes T via a
// shuffle-tree ordered matrix product (replaces the 1-thread serial kernel);
// erfinv's log1pf replaced by hardware v_log_f32 on fma(-x,x,1).
// ---------------------------------------------------------------------------

#define NBATCH 256
#define NDIM   8192u

__host__ __device__ __forceinline__ unsigned rotl32(unsigned v, unsigned d) {
  return (v << d) | (v >> (32u - d));
}

// Threefry-2x32, 20 rounds, exactly as jax._src.prng.threefry2x32.
__host__ __device__ inline void tf2x32(unsigned k0, unsigned k1,
                                       unsigned x0, unsigned x1,
                                       unsigned& o0, unsigned& o1) {
  const unsigned k2 = k0 ^ k1 ^ 0x1BD11BDAu;
  x0 += k0; x1 += k1;
#define TF_R(r) { x0 += x1; x1 = rotl32(x1, r); x1 ^= x0; }
  TF_R(13u) TF_R(15u) TF_R(26u) TF_R(6u)
  x0 += k1; x1 += k2 + 1u;
  TF_R(17u) TF_R(29u) TF_R(16u) TF_R(24u)
  x0 += k2; x1 += k0 + 2u;
  TF_R(13u) TF_R(15u) TF_R(26u) TF_R(6u)
  x0 += k0; x1 += k1 + 3u;
  TF_R(17u) TF_R(29u) TF_R(16u) TF_R(24u)
  x0 += k1; x1 += k2 + 4u;
  TF_R(13u) TF_R(15u) TF_R(26u) TF_R(6u)
  x0 += k2; x1 += k0 + 5u;
#undef TF_R
  o0 = x0; o1 = x1;
}

// JAX _uniform(lo=nextafter(-1,0), hi=1) for float32 from 32 random bits.
__device__ __forceinline__ float bits_to_u(unsigned bits) {
  float f = __uint_as_float((bits >> 9) | 0x3f800000u) - 1.0f; // [0, 1-2^-23]
  const float LO = -0.99999994f;
  return fmaxf(LO, fmaf(f, 2.0f, LO));
}

// Giles erfinvf (XLA ErfInv32 coefficients); w via hardware log:
// w = -log(1-x^2), 1-x^2 computed with a single-rounding fma.
__device__ __forceinline__ float erfinv_f(float x) {
  float w = -__logf(fmaf(-x, x, 1.0f));
  float p;
  if (w < 5.0f) {
    w -= 2.5f;
    p = 2.81022636e-08f;
    p = fmaf(p, w, 3.43273939e-07f);
    p = fmaf(p, w, -3.5233877e-06f);
    p = fmaf(p, w, -4.39150654e-06f);
    p = fmaf(p, w, 0.00021858087f);
    p = fmaf(p, w, -0.00125372503f);
    p = fmaf(p, w, -0.00417768164f);
    p = fmaf(p, w, 0.246640727f);
    p = fmaf(p, w, 1.50140941f);
  } else {
    w = sqrtf(w) - 3.0f;
    p = -0.000200214257f;
    p = fmaf(p, w, 0.000100950558f);
    p = fmaf(p, w, 0.00134934322f);
    p = fmaf(p, w, -0.00367342844f);
    p = fmaf(p, w, 0.00573950773f);
    p = fmaf(p, w, -0.0076224613f);
    p = fmaf(p, w, 0.00943887047f);
    p = fmaf(p, w, 1.00167406f);
    p = fmaf(p, w, 2.83297682f);
  }
  return p * x;
}

__device__ __forceinline__ float2 cmul(float2 a, float2 b) {
  return make_float2(a.x * b.x - a.y * b.y, a.x * b.y + a.y * b.x);
}
__device__ __forceinline__ float2 cadd(float2 a, float2 b) {
  return make_float2(a.x + b.x, a.y + b.y);
}

// Effective 2x2 linear map of gate g (0..77); includes the aliasing bug:
// e' = m00 e + m01 o ; o' = m10 e' + m11 o
//   -> G = [[m00, m01], [m10*m00, m10*m01 + m11]]
__device__ __forceinline__ void eff_gate(int g, const float* rx, const float* ry,
                                         const float* rz, float2& G00, float2& G01,
                                         float2& G10, float2& G11) {
  if (g >= 78) { // identity padding
    G00 = make_float2(1.f, 0.f); G01 = make_float2(0.f, 0.f);
    G10 = make_float2(0.f, 0.f); G11 = make_float2(1.f, 0.f);
    return;
  }
  int axis = (g >= 52) ? 2 : ((g >= 26) ? 1 : 0);
  int w = g - axis * 26;
  float a = ((axis == 0) ? rx[w] : (axis == 1) ? ry[w] : rz[w]) * 0.5f;
  float s, c;
  sincosf(a, &s, &c);
  float2 m00, m01, m10, m11;
  if (axis == 0) {        // RX: [[c, -is], [-is, c]]
    m00 = make_float2(c, 0.f); m01 = make_float2(0.f, -s);
    m10 = make_float2(0.f, -s); m11 = make_float2(c, 0.f);
  } else if (axis == 1) { // RY: [[c, -s], [s, c]]
    m00 = make_float2(c, 0.f); m01 = make_float2(-s, 0.f);
    m10 = make_float2(s, 0.f); m11 = make_float2(c, 0.f);
  } else {                // RZ: diag(e^{-ia/2}, e^{ia/2})
    m00 = make_float2(c, -s); m01 = make_float2(0.f, 0.f);
    m10 = make_float2(0.f, 0.f); m11 = make_float2(c, s);
  }
  G00 = m00; G01 = m01;
  G10 = cmul(m10, m00);
  G11 = cadd(cmul(m10, m01), m11);
}

// One block per batch row; 1024 threads x 8 columns each.
__global__ __launch_bounds__(1024) void fused_kernel(
    const float* __restrict__ rx, const float* __restrict__ ry,
    const float* __restrict__ rz, float* __restrict__ out,
    unsigned kr0, unsigned kr1, unsigned ki0, unsigned ki1) {
  const int b = blockIdx.x;
  const int t = threadIdx.x;
  const unsigned base = (unsigned)b * NDIM;

  // --- wave 0: ordered product of 78 gates via suffix-scan shuffle tree ---
  float T00r = 0.f, T00i = 0.f, T10r = 0.f, T10i = 0.f;
  if (t < 64) {
    float2 A00, A01, A10, A11, B00, B01, B10, B11;
    eff_gate(2 * t, rx, ry, rz, A00, A01, A10, A11);
    eff_gate(2 * t + 1, rx, ry, rz, B00, B01, B10, B11);
    // P = B * A (later gate on the left)
    float2 P00 = cadd(cmul(B00, A00), cmul(B01, A10));
    float2 P01 = cadd(cmul(B00, A01), cmul(B01, A11));
    float2 P10 = cadd(cmul(B10, A00), cmul(B11, A10));
    float2 P11 = cadd(cmul(B10, A01), cmul(B11, A11));
#pragma unroll
    for (int s = 1; s < 64; s <<= 1) {
      float2 Q00, Q01, Q10, Q11;
      Q00.x = __shfl(P00.x, t + s); Q00.y = __shfl(P00.y, t + s);
      Q01.x = __shfl(P01.x, t + s); Q01.y = __shfl(P01.y, t + s);
      Q10.x = __shfl(P10.x, t + s); Q10.y = __shfl(P10.y, t + s);
      Q11.x = __shfl(P11.x, t + s); Q11.y = __shfl(P11.y, t + s);
      if (t + s < 64) { // Q * P, order-preserving
        float2 R00 = cadd(cmul(Q00, P00), cmul(Q01, P10));
        float2 R01 = cadd(cmul(Q00, P01), cmul(Q01, P11));
        float2 R10 = cadd(cmul(Q10, P00), cmul(Q11, P10));
        float2 R11 = cadd(cmul(Q10, P01), cmul(Q11, P11));
        P00 = R00; P01 = R01; P10 = R10; P11 = R11;
      }
    }
    // lane 0 now holds the full product; state = T * (1,0) = (P00, P10)
    T00r = P00.x; T00i = P00.y; T10r = P10.x; T10i = P10.y;
  }

  // --- all threads: 8 columns of complex noise ---
  float re[8], im[8];
#pragma unroll
  for (int k = 0; k < 8; ++k) {
    unsigned j = base + (unsigned)t * 8u + (unsigned)k;
    unsigned y0, y1;
    tf2x32(kr0, kr1, 0u, j, y0, y1);
    re[k] = erfinv_f(bits_to_u(y0 ^ y1)) * 0.01f;
    tf2x32(ki0, ki1, 0u, j, y0, y1);
    im[k] = erfinv_f(bits_to_u(y0 ^ y1)) * 0.01f;
  }
  if (t == 0) { // columns 0,1 carry the circuit amplitudes (thread 0 owns them)
    re[0] += T00r; im[0] += T00i;
    re[1] += T10r; im[1] += T10i;
  }

  float sumsq = 0.0f;
  float a[8];
#pragma unroll
  for (int k = 0; k < 8; ++k) {
    float s2 = fmaf(re[k], re[k], im[k] * im[k]);
    sumsq += s2;
    a[k] = sqrtf(s2);
  }

  // block-wide reduction: wave64 shuffle, then 16 wave partials via LDS
#pragma unroll
  for (int off = 32; off; off >>= 1) sumsq += __shfl_down(sumsq, off);
  __shared__ float wsum[16];
  __shared__ float s_rnorm;
  if ((t & 63) == 0) wsum[t >> 6] = sumsq;
  __syncthreads();
  if (t < 64) {
    float v = (t < 16) ? wsum[t] : 0.0f;
#pragma unroll
    for (int off = 8; off; off >>= 1) v += __shfl_xor(v, off);
    if (t == 0) s_rnorm = rsqrtf(v);
  }
  __syncthreads();
  const float rn = s_rnorm;

  float4 o0 = make_float4(a[0] * rn, a[1] * rn, a[2] * rn, a[3] * rn);
  float4 o1 = make_float4(a[4] * rn, a[5] * rn, a[6] * rn, a[7] * rn);
  float4* op = (float4*)(out + base + (unsigned)t * 8u);
  op[0] = o0;
  op[1] = o1;
}

extern "C" void kernel_launch(void* const* d_in, const int* in_sizes, int n_in,
                              void* d_out, int out_size, void* d_ws, size_t ws_size,
                              hipStream_t stream) {
  (void)in_sizes; (void)n_in; (void)out_size; (void)ws_size; (void)d_ws;
  // inputs: 0=x (unused), 1=rx_params(26), 2=ry_params(26), 3=rz_params(26)
  const float* rx = (const float*)d_in[1];
  const float* ry = (const float*)d_in[2];
  const float* rz = (const float*)d_in[3];
  float* out = (float*)d_out;

  // jax.random.key(42) -> (0,42); partitionable split for complex normal:
  // key_re = TF(key,(0,0)), key_im = TF(key,(0,1)).
  unsigned kr0, kr1, ki0, ki1;
  tf2x32(0u, 42u, 0u, 0u, kr0, kr1);
  tf2x32(0u, 42u, 0u, 1u, ki0, ki1);

  fused_kernel<<<NBATCH, 1024, 0, stream>>>(rx, ry, rz, out, kr0, kr1, ki0, ki1);
}

// Round 4
// 19.001 us; speedup vs baseline: 2.4858x; 1.0383x over previous
//
#include <hip/hip_runtime.h>

// ---------------------------------------------------------------------------
// QuantumLayer: reference collapses to
//   T = ordered product of 78 effective 2x2 gates applied to (1,0)  (batch-invariant)
//   out[b,j] = |T_j? + noise[b,j]| / norm_b
// noise = jax.random.normal(key(42),(256,8192),c64)*0.01, threefry2x32
// partitionable mode (verified bit-match: absmax 1.2e-4 vs 8.6e-4 threshold).
// Round 4: fix round-3 compile error — __sqrtf/__frsqrt_rn are not HIP
// device intrinsics; use __builtin_amdgcn_sqrtf / __builtin_amdgcn_rsqf
// (v_sqrt_f32 / v_rsq_f32). Rest unchanged: RZ product collapsed to a single
// phase, 52-gate shuffle tree with native __sincosf, __builtin_rotateleft32.
// ---------------------------------------------------------------------------

#define NBATCH 256
#define NDIM   8192u

// Threefry-2x32, 20 rounds, exactly as jax._src.prng.threefry2x32.
__host__ __device__ inline void tf2x32(unsigned k0, unsigned k1,
                                       unsigned x0, unsigned x1,
                                       unsigned& o0, unsigned& o1) {
  const unsigned k2 = k0 ^ k1 ^ 0x1BD11BDAu;
  x0 += k0; x1 += k1;
#define TF_R(r) { x0 += x1; x1 = __builtin_rotateleft32(x1, r); x1 ^= x0; }
  TF_R(13u) TF_R(15u) TF_R(26u) TF_R(6u)
  x0 += k1; x1 += k2 + 1u;
  TF_R(17u) TF_R(29u) TF_R(16u) TF_R(24u)
  x0 += k2; x1 += k0 + 2u;
  TF_R(13u) TF_R(15u) TF_R(26u) TF_R(6u)
  x0 += k0; x1 += k1 + 3u;
  TF_R(17u) TF_R(29u) TF_R(16u) TF_R(24u)
  x0 += k1; x1 += k2 + 4u;
  TF_R(13u) TF_R(15u) TF_R(26u) TF_R(6u)
  x0 += k2; x1 += k0 + 5u;
#undef TF_R
  o0 = x0; o1 = x1;
}

// JAX _uniform(lo=nextafter(-1,0), hi=1): f in [0,1), u = f*2 + LO.
// (The max(lo,.) clamp is dead since f >= 0.)
__device__ __forceinline__ float bits_to_u(unsigned bits) {
  float f = __uint_as_float((bits >> 9) | 0x3f800000u) - 1.0f;
  return fmaf(f, 2.0f, -0.99999994f);
}

// Giles erfinvf (XLA ErfInv32 coefficients); w = -log(1-x^2) via v_log_f32.
__device__ __forceinline__ float erfinv_f(float x) {
  float w = -__logf(fmaf(-x, x, 1.0f));
  float p;
  if (w < 5.0f) {
    w -= 2.5f;
    p = 2.81022636e-08f;
    p = fmaf(p, w, 3.43273939e-07f);
    p = fmaf(p, w, -3.5233877e-06f);
    p = fmaf(p, w, -4.39150654e-06f);
    p = fmaf(p, w, 0.00021858087f);
    p = fmaf(p, w, -0.00125372503f);
    p = fmaf(p, w, -0.00417768164f);
    p = fmaf(p, w, 0.246640727f);
    p = fmaf(p, w, 1.50140941f);
  } else {
    w = __builtin_amdgcn_sqrtf(w) - 3.0f;
    p = -0.000200214257f;
    p = fmaf(p, w, 0.000100950558f);
    p = fmaf(p, w, 0.00134934322f);
    p = fmaf(p, w, -0.00367342844f);
    p = fmaf(p, w, 0.00573950773f);
    p = fmaf(p, w, -0.0076224613f);
    p = fmaf(p, w, 0.00943887047f);
    p = fmaf(p, w, 1.00167406f);
    p = fmaf(p, w, 2.83297682f);
  }
  return p * x;
}

__device__ __forceinline__ float2 cmul(float2 a, float2 b) {
  return make_float2(a.x * b.x - a.y * b.y, a.x * b.y + a.y * b.x);
}
__device__ __forceinline__ float2 cadd(float2 a, float2 b) {
  return make_float2(a.x + b.x, a.y + b.y);
}

// One block per batch row; 1024 threads x 8 columns each.
__global__ __launch_bounds__(1024) void fused_kernel(
    const float* __restrict__ rx, const float* __restrict__ ry,
    const float* __restrict__ rz, float* __restrict__ out,
    unsigned kr0, unsigned kr1, unsigned ki0, unsigned ki1) {
  const int b = blockIdx.x;
  const int t = threadIdx.x;
  const unsigned base = (unsigned)b * NDIM;

  // --- wave 0: T = (RZ phase) * ordered product of 52 RX/RY gates --------
  // Effective gate with the aliasing bug: e' = m00 e + m01 o; o' = m10 e' + m11 o
  //   -> G = [[m00, m01], [m10*m00, m10*m01 + m11]]
  // RX (real c, s): G = [[(c,0),(0,-s)], [(0,-s*c),(c-s^2,0)]]
  // RY:             G = [[(c,0),(-s,0)], [(s*c,0),(c-s^2,0)]]
  // RZ is diagonal (m10=0, bug no-op): product = diag(e^{-iS/2}, e^{+iS/2}),
  // S = sum(rz).
  float T00r = 0.f, T00i = 0.f, T10r = 0.f, T10i = 0.f;
  if (t < 64) {
    // RZ phase sum (all lanes)
    float rzv = (t < 26) ? rz[t] : 0.0f;
#pragma unroll
    for (int off = 32; off; off >>= 1) rzv += __shfl_xor(rzv, off);
    float sh, ch;
    __sincosf(0.5f * rzv, &sh, &ch);

    // one gate per lane: lanes 0..25 RX, 26..51 RY, rest identity
    float2 P00, P01, P10, P11;
    if (t < 52) {
      bool is_ry = (t >= 26);
      float ang = 0.5f * (is_ry ? ry[t - 26] : rx[t]);
      float s, c;
      __sincosf(ang, &s, &c);
      float cs = c - s * s;      // G11 real part (both axes)
      float sc = s * c;
      P00 = make_float2(c, 0.f);
      P11 = make_float2(cs, 0.f);
      if (is_ry) {
        P01 = make_float2(-s, 0.f);
        P10 = make_float2(sc, 0.f);
      } else {
        P01 = make_float2(0.f, -s);
        P10 = make_float2(0.f, -sc);
      }
    } else {
      P00 = make_float2(1.f, 0.f); P01 = make_float2(0.f, 0.f);
      P10 = make_float2(0.f, 0.f); P11 = make_float2(1.f, 0.f);
    }
    // ordered suffix-scan: P_l <- P_{l+s} * P_l ; lane 0 ends with G51..G0
#pragma unroll
    for (int s = 1; s < 64; s <<= 1) {
      float2 Q00, Q01, Q10, Q11;
      Q00.x = __shfl(P00.x, t + s); Q00.y = __shfl(P00.y, t + s);
      Q01.x = __shfl(P01.x, t + s); Q01.y = __shfl(P01.y, t + s);
      Q10.x = __shfl(P10.x, t + s); Q10.y = __shfl(P10.y, t + s);
      Q11.x = __shfl(P11.x, t + s); Q11.y = __shfl(P11.y, t + s);
      if (t + s < 64) {
        float2 R00 = cadd(cmul(Q00, P00), cmul(Q01, P10));
        float2 R01 = cadd(cmul(Q00, P01), cmul(Q01, P11));
        float2 R10 = cadd(cmul(Q10, P00), cmul(Q11, P10));
        float2 R11 = cadd(cmul(Q10, P01), cmul(Q11, P11));
        P00 = R00; P01 = R01; P10 = R10; P11 = R11;
      }
    }
    // column T*(1,0) = (P00, P10); apply RZ phases e^{-ih}, e^{+ih}
    T00r = fmaf(P00.y, sh, P00.x * ch);
    T00i = fmaf(-P00.x, sh, P00.y * ch);
    T10r = fmaf(-P10.y, sh, P10.x * ch);
    T10i = fmaf(P10.x, sh, P10.y * ch);
  }

  // --- all threads: 8 columns of complex noise ---
  float re[8], im[8];
#pragma unroll
  for (int k = 0; k < 8; ++k) {
    unsigned j = base + (unsigned)t * 8u + (unsigned)k;
    unsigned y0, y1;
    tf2x32(kr0, kr1, 0u, j, y0, y1);
    re[k] = erfinv_f(bits_to_u(y0 ^ y1)) * 0.01f;
    tf2x32(ki0, ki1, 0u, j, y0, y1);
    im[k] = erfinv_f(bits_to_u(y0 ^ y1)) * 0.01f;
  }
  if (t == 0) { // columns 0,1 carry the circuit amplitudes
    re[0] += T00r; im[0] += T00i;
    re[1] += T10r; im[1] += T10i;
  }

  float sumsq = 0.0f;
  float a[8];
#pragma unroll
  for (int k = 0; k < 8; ++k) {
    float s2 = fmaf(re[k], re[k], im[k] * im[k]);
    sumsq += s2;
    a[k] = __builtin_amdgcn_sqrtf(s2);
  }

  // block-wide reduction: wave64 shuffle, then 16 wave partials via LDS
#pragma unroll
  for (int off = 32; off; off >>= 1) sumsq += __shfl_down(sumsq, off);
  __shared__ float wsum[16];
  __shared__ float s_rnorm;
  if ((t & 63) == 0) wsum[t >> 6] = sumsq;
  __syncthreads();
  if (t < 64) {
    float v = (t < 16) ? wsum[t] : 0.0f;
#pragma unroll
    for (int off = 8; off; off >>= 1) v += __shfl_xor(v, off);
    if (t == 0) s_rnorm = __builtin_amdgcn_rsqf(v);
  }
  __syncthreads();
  const float rn = s_rnorm;

  float4 o0 = make_float4(a[0] * rn, a[1] * rn, a[2] * rn, a[3] * rn);
  float4 o1 = make_float4(a[4] * rn, a[5] * rn, a[6] * rn, a[7] * rn);
  float4* op = (float4*)(out + base + (unsigned)t * 8u);
  op[0] = o0;
  op[1] = o1;
}

extern "C" void kernel_launch(void* const* d_in, const int* in_sizes, int n_in,
                              void* d_out, int out_size, void* d_ws, size_t ws_size,
                              hipStream_t stream) {
  (void)in_sizes; (void)n_in; (void)out_size; (void)ws_size; (void)d_ws;
  // inputs: 0=x (unused by the reference), 1=rx(26), 2=ry(26), 3=rz(26)
  const float* rx = (const float*)d_in[1];
  const float* ry = (const float*)d_in[2];
  const float* rz = (const float*)d_in[3];
  float* out = (float*)d_out;

  // jax.random.key(42) -> (0,42); partitionable split for complex normal:
  // key_re = TF(key,(0,0)), key_im = TF(key,(0,1)).
  unsigned kr0, kr1, ki0, ki1;
  tf2x32(0u, 42u, 0u, 0u, kr0, kr1);
  tf2x32(0u, 42u, 0u, 1u, ki0, ki1);

  fused_kernel<<<NBATCH, 1024, 0, stream>>>(rx, ry, rz, out, kr0, kr1, ki0, ki1);
}

// Round 5
// 18.533 us; speedup vs baseline: 2.5486x; 1.0253x over previous
//
#include <hip/hip_runtime.h>

// ---------------------------------------------------------------------------
// QuantumLayer: reference collapses to
//   T = ordered product of 78 effective 2x2 gates applied to (1,0)  (batch-invariant)
//   out[b,j] = |T_j? + noise[b,j]| / norm_b
// noise = jax.random.normal(key(42),(256,8192),c64)*0.01, threefry2x32
// partitionable mode (verified bit-match: absmax 1.2e-4 vs 8.6e-4 threshold).
// Round 5: (a) gate tree in REAL arithmetic — K=diag(1,i) conjugation makes
// the buggy RX gate real and identical in form to the RY gate
// ([[c,-s],[sc,c-s^2]]); two half-wave 5-level suffix scans in wave 0.
// (b) erfinv long path behind an explicit wave-uniform __ballot skip.
// Model: ~5.5us VALU floor (threefry) + ~1us ramp/tail + ~11us launch
// overhead; this round removes most of the remaining tree/branch fat.
// ---------------------------------------------------------------------------

#define NBATCH 256
#define NDIM   8192u

// Threefry-2x32, 20 rounds, exactly as jax._src.prng.threefry2x32.
__host__ __device__ inline void tf2x32(unsigned k0, unsigned k1,
                                       unsigned x0, unsigned x1,
                                       unsigned& o0, unsigned& o1) {
  const unsigned k2 = k0 ^ k1 ^ 0x1BD11BDAu;
  x0 += k0; x1 += k1;
#define TF_R(r) { x0 += x1; x1 = __builtin_rotateleft32(x1, r); x1 ^= x0; }
  TF_R(13u) TF_R(15u) TF_R(26u) TF_R(6u)
  x0 += k1; x1 += k2 + 1u;
  TF_R(17u) TF_R(29u) TF_R(16u) TF_R(24u)
  x0 += k2; x1 += k0 + 2u;
  TF_R(13u) TF_R(15u) TF_R(26u) TF_R(6u)
  x0 += k0; x1 += k1 + 3u;
  TF_R(17u) TF_R(29u) TF_R(16u) TF_R(24u)
  x0 += k1; x1 += k2 + 4u;
  TF_R(13u) TF_R(15u) TF_R(26u) TF_R(6u)
  x0 += k2; x1 += k0 + 5u;
#undef TF_R
  o0 = x0; o1 = x1;
}

// JAX _uniform(lo=nextafter(-1,0), hi=1): f in [0,1), u = f*2 + LO.
__device__ __forceinline__ float bits_to_u(unsigned bits) {
  float f = __uint_as_float((bits >> 9) | 0x3f800000u) - 1.0f;
  return fmaf(f, 2.0f, -0.99999994f);
}

// Giles erfinvf (XLA ErfInv32 coefficients); w = -log(1-x^2) via v_log_f32.
// Long path (w>=5, P~0.34%/lane) guarded by a wave-uniform ballot so the
// sqrt + 9-fma chain is skipped when no lane needs it (~80% of slots).
__device__ __forceinline__ float erfinv_f(float x) {
  float w = -__logf(fmaf(-x, x, 1.0f));
  float ws = w - 2.5f;
  float p = 2.81022636e-08f;
  p = fmaf(p, ws, 3.43273939e-07f);
  p = fmaf(p, ws, -3.5233877e-06f);
  p = fmaf(p, ws, -4.39150654e-06f);
  p = fmaf(p, ws, 0.00021858087f);
  p = fmaf(p, ws, -0.00125372503f);
  p = fmaf(p, ws, -0.00417768164f);
  p = fmaf(p, ws, 0.246640727f);
  p = fmaf(p, ws, 1.50140941f);
  if (__ballot(w >= 5.0f) != 0ull) {
    if (w >= 5.0f) {
      float wl = __builtin_amdgcn_sqrtf(w) - 3.0f;
      float q = -0.000200214257f;
      q = fmaf(q, wl, 0.000100950558f);
      q = fmaf(q, wl, 0.00134934322f);
      q = fmaf(q, wl, -0.00367342844f);
      q = fmaf(q, wl, 0.00573950773f);
      q = fmaf(q, wl, -0.0076224613f);
      q = fmaf(q, wl, 0.00943887047f);
      q = fmaf(q, wl, 1.00167406f);
      q = fmaf(q, wl, 2.83297682f);
      p = q;
    }
  }
  return p * x;
}

// One block per batch row; 1024 threads x 8 complex columns each.
__global__ __launch_bounds__(1024) void fused_kernel(
    const float* __restrict__ rx, const float* __restrict__ ry,
    const float* __restrict__ rz, float* __restrict__ out,
    unsigned kr0, unsigned kr1, unsigned ki0, unsigned ki1) {
  const int b = blockIdx.x;
  const int t = threadIdx.x;
  const unsigned base = (unsigned)b * NDIM;

  // --- wave 0: T via two half-wave REAL suffix scans + RZ phase ----------
  // Effective gate with the aliasing bug: G = [[m00,m01],[m10*m00, m10*m01+m11]].
  // K = diag(1,i):  K*G_RX*K^-1 = [[c,-s],[s*c, c-s^2]]  (real), which is
  // exactly G_RY's form. With Mx = prod(RX real mats), My = prod(RY real mats):
  //   state after RX+RY chains = (ya*xa - i*yb*xc, yc*xa - i*yd*xc)
  // where (xa,xc) = Mx[:,0], [ya yb; yc yd] = My. RZ chain is diagonal
  // (bug no-op): multiply by e^{-iS/2}, e^{+iS/2}, S = sum(rz).
  float T00r = 0.f, T00i = 0.f, T10r = 0.f, T10i = 0.f;
  if (t < 64) {
    float rzv = (t < 26) ? rz[t] : 0.0f;
#pragma unroll
    for (int off = 32; off; off >>= 1) rzv += __shfl_xor(rzv, off);
    float sh, ch;
    __sincosf(0.5f * rzv, &sh, &ch);

    // lanes 0..31: RX chain; lanes 32..63: RY chain; one real 2x2 per lane
    const int idx = t & 31;
    float A, Bv, C, D;
    if (idx < 26) {
      float s, c;
      __sincosf(0.5f * ((t < 32) ? rx[idx] : ry[idx]), &s, &c);
      A = c; Bv = -s; C = s * c; D = fmaf(-s, s, c);
    } else {
      A = 1.f; Bv = 0.f; C = 0.f; D = 1.f;
    }
    // ordered suffix scan within each 32-lane half: P_l <- P_{l+s} * P_l
#pragma unroll
    for (int s = 1; s < 32; s <<= 1) {
      float qa = __shfl(A, t + s), qb = __shfl(Bv, t + s);
      float qc = __shfl(C, t + s), qd = __shfl(D, t + s);
      if (idx + s < 32) {
        float ra = fmaf(qa, A, qb * C);
        float rb = fmaf(qa, Bv, qb * D);
        float rc = fmaf(qc, A, qd * C);
        float rd = fmaf(qc, Bv, qd * D);
        A = ra; Bv = rb; C = rc; D = rd;
      }
    }
    // lane 0 holds Mx, lane 32 holds My; pull My down to all lanes
    float ya = __shfl(A, 32), yb = __shfl(Bv, 32);
    float yc = __shfl(C, 32), yd = __shfl(D, 32);
    float t00r = ya * A,  t00i = -yb * C;   // valid on lane 0 (A=xa, C=xc)
    float t10r = yc * A,  t10i = -yd * C;
    T00r = fmaf(t00r, ch,  t00i * sh);
    T00i = fmaf(t00i, ch, -t00r * sh);
    T10r = fmaf(t10r, ch, -t10i * sh);
    T10i = fmaf(t10i, ch,  t10r * sh);
  }

  // --- all threads: 8 columns of complex noise ---
  float re[8], im[8];
#pragma unroll
  for (int k = 0; k < 8; ++k) {
    unsigned j = base + (unsigned)t * 8u + (unsigned)k;
    unsigned y0, y1;
    tf2x32(kr0, kr1, 0u, j, y0, y1);
    re[k] = erfinv_f(bits_to_u(y0 ^ y1)) * 0.01f;
    tf2x32(ki0, ki1, 0u, j, y0, y1);
    im[k] = erfinv_f(bits_to_u(y0 ^ y1)) * 0.01f;
  }
  if (t == 0) { // columns 0,1 carry the circuit amplitudes
    re[0] += T00r; im[0] += T00i;
    re[1] += T10r; im[1] += T10i;
  }

  float sumsq = 0.0f;
  float a[8];
#pragma unroll
  for (int k = 0; k < 8; ++k) {
    float s2 = fmaf(re[k], re[k], im[k] * im[k]);
    sumsq += s2;
    a[k] = __builtin_amdgcn_sqrtf(s2);
  }

  // block-wide reduction: wave64 shuffle, then 16 wave partials via LDS
#pragma unroll
  for (int off = 32; off; off >>= 1) sumsq += __shfl_down(sumsq, off);
  __shared__ float wsum[16];
  __shared__ float s_rnorm;
  if ((t & 63) == 0) wsum[t >> 6] = sumsq;
  __syncthreads();
  if (t < 64) {
    float v = (t < 16) ? wsum[t] : 0.0f;
#pragma unroll
    for (int off = 8; off; off >>= 1) v += __shfl_xor(v, off);
    if (t == 0) s_rnorm = __builtin_amdgcn_rsqf(v);
  }
  __syncthreads();
  const float rn = s_rnorm;

  float4 o0 = make_float4(a[0] * rn, a[1] * rn, a[2] * rn, a[3] * rn);
  float4 o1 = make_float4(a[4] * rn, a[5] * rn, a[6] * rn, a[7] * rn);
  float4* op = (float4*)(out + base + (unsigned)t * 8u);
  op[0] = o0;
  op[1] = o1;
}

extern "C" void kernel_launch(void* const* d_in, const int* in_sizes, int n_in,
                              void* d_out, int out_size, void* d_ws, size_t ws_size,
                              hipStream_t stream) {
  (void)in_sizes; (void)n_in; (void)out_size; (void)ws_size; (void)d_ws;
  // inputs: 0=x (unused by the reference), 1=rx(26), 2=ry(26), 3=rz(26)
  const float* rx = (const float*)d_in[1];
  const float* ry = (const float*)d_in[2];
  const float* rz = (const float*)d_in[3];
  float* out = (float*)d_out;

  // jax.random.key(42) -> (0,42); partitionable split for complex normal:
  // key_re = TF(key,(0,0)), key_im = TF(key,(0,1)).
  unsigned kr0, kr1, ki0, ki1;
  tf2x32(0u, 42u, 0u, 0u, kr0, kr1);
  tf2x32(0u, 42u, 0u, 1u, ki0, ki1);

  fused_kernel<<<NBATCH, 1024, 0, stream>>>(rx, ry, rz, out, kr0, kr1, ki0, ki1);
}

// Round 6
// 17.868 us; speedup vs baseline: 2.6434x; 1.0372x over previous
//
#include <hip/hip_runtime.h>

// ---------------------------------------------------------------------------
// QuantumLayer: reference collapses to
//   T = ordered product of 78 effective 2x2 gates applied to (1,0)  (batch-invariant)
//   out[b,j] = |T_j? + noise[b,j]| / norm_b
// noise = jax.random.normal(key(42),(256,8192),c64)*0.01, threefry2x32
// partitionable mode (verified bit-match: absmax 1.2e-4 vs 8.6e-4 threshold).
// Round 6: (a) single-barrier norm reduction (all waves redundantly reduce
// 16 LDS partials — drops a barrier round-trip); (b) thread->column remap so
// each dwordx4 store is a dense 1KiB/wave write; (c) 0.01 noise scale folded
// into the erfinv polynomial coefficients.
// Model: ~5.3us VALU-issue floor (threefry 20 rounds, bit-exact, 1120 of
// ~1600 instr/thread) + ramp/tail + ~10-11us graph/dispatch overhead.
// Pre-commit: if this lands >18.1us, we are at the floor -> ROOFLINE.
// ---------------------------------------------------------------------------

#define NBATCH 256
#define NDIM   8192u

// Threefry-2x32, 20 rounds, exactly as jax._src.prng.threefry2x32.
__host__ __device__ inline void tf2x32(unsigned k0, unsigned k1,
                                       unsigned x0, unsigned x1,
                                       unsigned& o0, unsigned& o1) {
  const unsigned k2 = k0 ^ k1 ^ 0x1BD11BDAu;
  x0 += k0; x1 += k1;
#define TF_R(r) { x0 += x1; x1 = __builtin_rotateleft32(x1, r); x1 ^= x0; }
  TF_R(13u) TF_R(15u) TF_R(26u) TF_R(6u)
  x0 += k1; x1 += k2 + 1u;
  TF_R(17u) TF_R(29u) TF_R(16u) TF_R(24u)
  x0 += k2; x1 += k0 + 2u;
  TF_R(13u) TF_R(15u) TF_R(26u) TF_R(6u)
  x0 += k0; x1 += k1 + 3u;
  TF_R(17u) TF_R(29u) TF_R(16u) TF_R(24u)
  x0 += k1; x1 += k2 + 4u;
  TF_R(13u) TF_R(15u) TF_R(26u) TF_R(6u)
  x0 += k2; x1 += k0 + 5u;
#undef TF_R
  o0 = x0; o1 = x1;
}

// JAX _uniform(lo=nextafter(-1,0), hi=1): f in [0,1), u = f*2 + LO.
__device__ __forceinline__ float bits_to_u(unsigned bits) {
  float f = __uint_as_float((bits >> 9) | 0x3f800000u) - 1.0f;
  return fmaf(f, 2.0f, -0.99999994f);
}

// Giles erfinvf (XLA ErfInv32 coefficients) PRE-SCALED by 0.01 (the noise
// amplitude): returns 0.01*erfinv(x). w = -log(1-x^2) via v_log_f32.
// Long path (w>=5, P~0.34%/lane) behind a wave-uniform ballot skip.
__device__ __forceinline__ float erfinv_scaled(float x) {
  float w = -__logf(fmaf(-x, x, 1.0f));
  float ws = w - 2.5f;
  float p = 2.81022636e-10f;
  p = fmaf(p, ws, 3.43273939e-09f);
  p = fmaf(p, ws, -3.5233877e-08f);
  p = fmaf(p, ws, -4.39150654e-08f);
  p = fmaf(p, ws, 2.1858087e-06f);
  p = fmaf(p, ws, -1.25372503e-05f);
  p = fmaf(p, ws, -4.17768164e-05f);
  p = fmaf(p, ws, 2.46640727e-03f);
  p = fmaf(p, ws, 1.50140941e-02f);
  if (__ballot(w >= 5.0f) != 0ull) {
    if (w >= 5.0f) {
      float wl = __builtin_amdgcn_sqrtf(w) - 3.0f;
      float q = -2.00214257e-06f;
      q = fmaf(q, wl, 1.00950558e-06f);
      q = fmaf(q, wl, 1.34934322e-05f);
      q = fmaf(q, wl, -3.67342844e-05f);
      q = fmaf(q, wl, 5.73950773e-05f);
      q = fmaf(q, wl, -7.6224613e-05f);
      q = fmaf(q, wl, 9.43887047e-05f);
      q = fmaf(q, wl, 1.00167406e-02f);
      q = fmaf(q, wl, 2.83297682e-02f);
      p = q;
    }
  }
  return p * x;
}

// One block per batch row; 1024 threads; thread t owns columns
// [4t, 4t+4) and [4096+4t, 4096+4t+4)  -> dense dwordx4 stores.
__global__ __launch_bounds__(1024) void fused_kernel(
    const float* __restrict__ rx, const float* __restrict__ ry,
    const float* __restrict__ rz, float* __restrict__ out,
    unsigned kr0, unsigned kr1, unsigned ki0, unsigned ki1) {
  const int b = blockIdx.x;
  const int t = threadIdx.x;
  const unsigned base = (unsigned)b * NDIM;

  // --- wave 0: T via two half-wave REAL suffix scans + RZ phase ----------
  // (verified round 5: K=diag(1,i) conjugation makes the buggy RX gate real,
  // same form as RY: [[c,-s],[s*c, c-s^2]]; RZ chain is a pure phase.)
  float T00r = 0.f, T00i = 0.f, T10r = 0.f, T10i = 0.f;
  if (t < 64) {
    float rzv = (t < 26) ? rz[t] : 0.0f;
#pragma unroll
    for (int off = 32; off; off >>= 1) rzv += __shfl_xor(rzv, off);
    float sh, ch;
    __sincosf(0.5f * rzv, &sh, &ch);

    const int idx = t & 31;
    float A, Bv, C, D;
    if (idx < 26) {
      float s, c;
      __sincosf(0.5f * ((t < 32) ? rx[idx] : ry[idx]), &s, &c);
      A = c; Bv = -s; C = s * c; D = fmaf(-s, s, c);
    } else {
      A = 1.f; Bv = 0.f; C = 0.f; D = 1.f;
    }
#pragma unroll
    for (int s = 1; s < 32; s <<= 1) {
      float qa = __shfl(A, t + s), qb = __shfl(Bv, t + s);
      float qc = __shfl(C, t + s), qd = __shfl(D, t + s);
      if (idx + s < 32) {
        float ra = fmaf(qa, A, qb * C);
        float rb = fmaf(qa, Bv, qb * D);
        float rc = fmaf(qc, A, qd * C);
        float rd = fmaf(qc, Bv, qd * D);
        A = ra; Bv = rb; C = rc; D = rd;
      }
    }
    float ya = __shfl(A, 32), yb = __shfl(Bv, 32);
    float yc = __shfl(C, 32), yd = __shfl(D, 32);
    float t00r = ya * A,  t00i = -yb * C;   // valid on lane 0 (A=xa, C=xc)
    float t10r = yc * A,  t10i = -yd * C;
    T00r = fmaf(t00r, ch,  t00i * sh);
    T00i = fmaf(t00i, ch, -t00r * sh);
    T10r = fmaf(t10r, ch, -t10i * sh);
    T10i = fmaf(t10i, ch,  t10r * sh);
  }

  // --- all threads: 8 complex columns of noise (two dense 4-col chunks) ---
  const unsigned j0 = base + 4u * (unsigned)t;          // cols 4t..4t+3
  const unsigned j1 = j0 + 4096u;                       // cols 4096+4t..
  float re[8], im[8];
#pragma unroll
  for (int k = 0; k < 8; ++k) {
    unsigned j = (k < 4) ? (j0 + (unsigned)k) : (j1 + (unsigned)(k - 4));
    unsigned y0, y1;
    tf2x32(kr0, kr1, 0u, j, y0, y1);
    re[k] = erfinv_scaled(bits_to_u(y0 ^ y1));
    tf2x32(ki0, ki1, 0u, j, y0, y1);
    im[k] = erfinv_scaled(bits_to_u(y0 ^ y1));
  }
  if (t == 0) { // columns 0,1 carry the circuit amplitudes
    re[0] += T00r; im[0] += T00i;
    re[1] += T10r; im[1] += T10i;
  }

  float sumsq = 0.0f;
  float a[8];
#pragma unroll
  for (int k = 0; k < 8; ++k) {
    float s2 = fmaf(re[k], re[k], im[k] * im[k]);
    sumsq += s2;
    a[k] = __builtin_amdgcn_sqrtf(s2);
  }

  // single-barrier block reduction: wave partials -> LDS -> every thread
  // redundantly sums 16 partials (broadcast reads) and computes rsq.
#pragma unroll
  for (int off = 32; off; off >>= 1) sumsq += __shfl_down(sumsq, off);
  __shared__ float wsum[16];
  if ((t & 63) == 0) wsum[t >> 6] = sumsq;
  __syncthreads();
  const float4* wp = (const float4*)wsum;
  float4 p0 = wp[0], p1 = wp[1], p2 = wp[2], p3 = wp[3];
  float v = (((p0.x + p0.y) + (p0.z + p0.w)) + ((p1.x + p1.y) + (p1.z + p1.w)))
          + (((p2.x + p2.y) + (p2.z + p2.w)) + ((p3.x + p3.y) + (p3.z + p3.w)));
  const float rn = __builtin_amdgcn_rsqf(v);

  float4 o0 = make_float4(a[0] * rn, a[1] * rn, a[2] * rn, a[3] * rn);
  float4 o1 = make_float4(a[4] * rn, a[5] * rn, a[6] * rn, a[7] * rn);
  *(float4*)(out + j0) = o0;
  *(float4*)(out + j1) = o1;
}

extern "C" void kernel_launch(void* const* d_in, const int* in_sizes, int n_in,
                              void* d_out, int out_size, void* d_ws, size_t ws_size,
                              hipStream_t stream) {
  (void)in_sizes; (void)n_in; (void)out_size; (void)ws_size; (void)d_ws;
  // inputs: 0=x (unused by the reference), 1=rx(26), 2=ry(26), 3=rz(26)
  const float* rx = (const float*)d_in[1];
  const float* ry = (const float*)d_in[2];
  const float* rz = (const float*)d_in[3];
  float* out = (float*)d_out;

  // jax.random.key(42) -> (0,42); partitionable split for complex normal:
  // key_re = TF(key,(0,0)), key_im = TF(key,(0,1)).
  unsigned kr0, kr1, ki0, ki1;
  tf2x32(0u, 42u, 0u, 0u, kr0, kr1);
  tf2x32(0u, 42u, 0u, 1u, ki0, ki1);

  fused_kernel<<<NBATCH, 1024, 0, stream>>>(rx, ry, rz, out, kr0, kr1, ki0, ki1);
}